// Round 5
// baseline (719.693 us; speedup 1.0000x reference)
//
#include <hip/hip_runtime.h>
#include <cstdint>
#include <cstddef>

typedef __bf16 bf16_t;
typedef _Float16 f16_t;
typedef __attribute__((ext_vector_type(8))) __bf16 bf16x8;
typedef __attribute__((ext_vector_type(4))) __bf16 bf16x4;
typedef __attribute__((ext_vector_type(2))) __bf16 bf16x2;
typedef __attribute__((ext_vector_type(8))) _Float16 f16x8;
typedef __attribute__((ext_vector_type(2))) _Float16 f16x2;
typedef __attribute__((ext_vector_type(4))) float floatx4;
typedef __attribute__((ext_vector_type(16))) float floatx16;

#define S_LEN 4096
#define DM 1024
#define NH 16
#define DKH 64
#define NSPLIT 4
#define KT_PER (S_LEN / 64 / NSPLIT)   // 16 kv-tiles per split

// scale * log2(e): folded into Q in the projection GEMM epilogue
#define QSCALE 0.1803368801111601f

__device__ __forceinline__ void async_b128(void* lds, const void* g) {
    __builtin_amdgcn_global_load_lds(
        (__attribute__((address_space(1))) void*)(uintptr_t)g,
        (__attribute__((address_space(3))) void*)lds,
        16, 0, 0);
}

__device__ __forceinline__ floatx4 mfma16(bf16x8 a, bf16x8 b, floatx4 c) {
    return __builtin_amdgcn_mfma_f32_16x16x32_bf16(a, b, c, 0, 0, 0);
}
__device__ __forceinline__ floatx16 mfma32(bf16x8 a, bf16x8 b, floatx16 c) {
    return __builtin_amdgcn_mfma_f32_32x32x16_bf16(a, b, c, 0, 0, 0);
}
__device__ __forceinline__ int f2i(float x) { return __builtin_bit_cast(int, x); }
__device__ __forceinline__ float i2f(int x) { return __builtin_bit_cast(float, x); }
__device__ __forceinline__ int p2i(bf16x2 x) { return __builtin_bit_cast(int, x); }
__device__ __forceinline__ bf16x2 i2p(int x) { return __builtin_bit_cast(bf16x2, x); }

// ------- fused fp32 -> bf16 conversion: inputs (12.58M) + weights (4.19M) ----
__global__ __launch_bounds__(256) void convert_all_kernel(
    const float* __restrict__ q, const float* __restrict__ k,
    const float* __restrict__ v, const float* __restrict__ wqf,
    const float* __restrict__ wkf, const float* __restrict__ wvf,
    const float* __restrict__ wof, bf16_t* __restrict__ dst_in,
    bf16_t* __restrict__ dst_w) {
    const size_t i = ((size_t)blockIdx.x * 256 + threadIdx.x) * 4;
    const float* s;
    bf16_t* d;
    size_t off;
    if (i < 12582912) {                  // 3 x 4194304 input elems
        const int r = (int)(i >> 22);
        s = (r == 0) ? q : (r == 1) ? k : v;
        off = i & 4194303;
        d = dst_in + (size_t)r * 4194304 + off;
    } else {                             // 4 x 1048576 weight elems
        const size_t j = i - 12582912;
        const int r = (int)(j >> 20);
        s = (r == 0) ? wqf : (r == 1) ? wkf : (r == 2) ? wvf : wof;
        off = j & 1048575;
        d = dst_w + (size_t)r * 1048576 + off;
    }
    const floatx4 val = *(const floatx4*)(s + off);
    bf16x4 o;
    o[0] = (bf16_t)val[0]; o[1] = (bf16_t)val[1];
    o[2] = (bf16_t)val[2]; o[3] = (bf16_t)val[3];
    *(bf16x4*)d = o;
}

// ------- GEMM: C[M,N] = (A[M,K] @ B[N,K]^T + bias[N]) * oscale, 128xBN tile -
template <int BN, typename OutT>
__device__ __forceinline__ void gemm_bt_body(const bf16_t* __restrict__ A,
                                             const bf16_t* __restrict__ B,
                                             const float* __restrict__ bias,
                                             OutT* __restrict__ C, float oscale) {
    constexpr int K = 1024, N = 1024;
    constexpr int NT = BN / 32;          // n-tiles of 16 per wave
    __shared__ bf16_t As[128 * 32];
    __shared__ bf16_t Bs[BN * 32];
    const int tid = threadIdx.x;
    const int wid = tid >> 6, lane = tid & 63;
    const int quad = lane >> 4, l16 = lane & 15;
    const int m0 = blockIdx.y * 128, n0 = blockIdx.x * BN;
    const int wm = (wid & 1) * 64, wn = (wid >> 1) * (BN / 2);

    floatx4 acc[4][NT] = {};

    for (int k0 = 0; k0 < K; k0 += 32) {
        __syncthreads();
#pragma unroll
        for (int i = 0; i < 2; ++i) {
            const int c = (i << 8) + tid;
            const int row = c >> 2;
            const int ko = (c & 3) << 3;
            const int lb = ((i << 8) + (wid << 6)) << 3;
            async_b128(&As[lb], A + (size_t)(m0 + row) * K + k0 + ko);
        }
#pragma unroll
        for (int i = 0; i < BN / 64; ++i) {
            const int c = (i << 8) + tid;
            const int row = c >> 2;
            const int ko = (c & 3) << 3;
            const int lb = ((i << 8) + (wid << 6)) << 3;
            async_b128(&Bs[lb], B + (size_t)(n0 + row) * K + k0 + ko);
        }
        __syncthreads();

        bf16x8 af[4], bfr[NT];
#pragma unroll
        for (int t = 0; t < 4; ++t)
            af[t] = *(const bf16x8*)&As[(wm + t * 16 + l16) * 32 + quad * 8];
#pragma unroll
        for (int t = 0; t < NT; ++t)
            bfr[t] = *(const bf16x8*)&Bs[(wn + t * 16 + l16) * 32 + quad * 8];
#pragma unroll
        for (int mt = 0; mt < 4; ++mt)
#pragma unroll
            for (int nt = 0; nt < NT; ++nt)
                acc[mt][nt] = mfma16(af[mt], bfr[nt], acc[mt][nt]);
    }

#pragma unroll
    for (int mt = 0; mt < 4; ++mt)
#pragma unroll
        for (int nt = 0; nt < NT; ++nt) {
            const int col = n0 + wn + nt * 16 + l16;
            const float bv = bias[col];
#pragma unroll
            for (int r = 0; r < 4; ++r) {
                const int row = m0 + wm + mt * 16 + quad * 4 + r;
                C[(size_t)row * N + col] = (OutT)((acc[mt][nt][r] + bv) * oscale);
            }
        }
}

__global__ __launch_bounds__(256) void gemm_qkv_kernel(
    const bf16_t* __restrict__ qx, const bf16_t* __restrict__ kx,
    const bf16_t* __restrict__ vx, const bf16_t* __restrict__ wq,
    const bf16_t* __restrict__ wk, const bf16_t* __restrict__ wv,
    const float* __restrict__ bq, const float* __restrict__ bk,
    const float* __restrict__ bv, bf16_t* __restrict__ Qp,
    bf16_t* __restrict__ Kp, bf16_t* __restrict__ Vp) {
    const int z = blockIdx.z;
    const bf16_t* A = (z == 0) ? qx : (z == 1) ? kx : vx;
    const bf16_t* B = (z == 0) ? wq : (z == 1) ? wk : wv;
    const float* bias = (z == 0) ? bq : (z == 1) ? bk : bv;
    bf16_t* C = (z == 0) ? Qp : (z == 1) ? Kp : Vp;
    gemm_bt_body<128, bf16_t>(A, B, bias, C, (z == 0) ? QSCALE : 1.0f);
}

__global__ __launch_bounds__(256) void gemm_out_kernel(
    const bf16_t* __restrict__ AO, const bf16_t* __restrict__ wo,
    const float* __restrict__ bo, float* __restrict__ out) {
    gemm_bt_body<64, float>(AO, wo, bo, out, 1.0f);
}

// ---------------- transpose Vp[4096,1024] -> Vt[1024,4096] ----------------
__global__ __launch_bounds__(256) void transpose_kernel(
    const bf16_t* __restrict__ in, bf16_t* __restrict__ out) {
    __shared__ bf16_t tile[64][65];
    const int tx = threadIdx.x & 63;
    const int ty = threadIdx.x >> 6;
    const int c0 = blockIdx.x * 64;
    const int r0 = blockIdx.y * 64;
#pragma unroll
    for (int i = 0; i < 16; ++i) {
        const int r = ty + i * 4;
        tile[r][tx] = in[(size_t)(r0 + r) * DM + c0 + tx];
    }
    __syncthreads();
#pragma unroll
    for (int i = 0; i < 16; ++i) {
        const int c = ty + i * 4;
        out[(size_t)(c0 + c) * S_LEN + r0 + tx] = tile[tx][c];
    }
}

// ---------------- flash attention, S^T formulation, kv-split ----------------
// Fixed-max softmax p=2^(s-3) is associative over kv. 4 waves/block share one
// 32KB double-buffered K/V tile; each wave owns 64 q columns.
// grid (16 q-blocks of 256, 16 heads, 4 splits), 256 thr.
__global__ __launch_bounds__(256, 4) void flash_kernel(
    const bf16_t* __restrict__ Q, const bf16_t* __restrict__ K,
    const bf16_t* __restrict__ Vt, f16_t* __restrict__ Opart,
    float* __restrict__ Lpart) {
    // 32 KB: Ks[2][4096] at 0, Vs[2][4096] at 8192; epilogue scratch aliased
    __shared__ bf16_t smem[16384];
    bf16_t* Ks = smem;
    bf16_t* Vs = smem + 8192;

    const int tid = threadIdx.x;
    const int wave = tid >> 6, lane = tid & 63;
    const int h32 = lane >> 5, c = lane & 31;
    const int head = blockIdx.y;
    const int sp = blockIdx.z;
    const int qbase = blockIdx.x * 256 + wave * 64;
    const int kv0 = sp * (S_LEN / NSPLIT);

    // Q B-frags in registers (pre-scaled by QSCALE): B[n=q=c][k=d]
    bf16x8 Qf[2][4];
#pragma unroll
    for (int nt = 0; nt < 2; ++nt)
#pragma unroll
        for (int s = 0; s < 4; ++s)
            Qf[nt][s] = *(const bf16x8*)(Q + (size_t)(qbase + nt * 32 + c) * DM +
                                         head * DKH + s * 16 + h32 * 8);

    floatx16 oa[2][2] = {};
    floatx4 la[2] = {};

    // staging: wave w stages chunks {2w, 2w+1} of K (d-split) and V (kv-split)
    const bf16_t* kptr = K + (size_t)(kv0 + lane) * DM + head * DKH + wave * 16;
    const bf16_t* vptr = Vt + (size_t)(head * DKH + lane) * S_LEN + kv0 + wave * 16;
    bf16_t* ksl = Ks + wave * 1024;
    bf16_t* vsl = Vs + wave * 1024;

    async_b128(ksl, kptr);       async_b128(ksl + 512, kptr + 8);
    async_b128(vsl, vptr);       async_b128(vsl + 512, vptr + 8);
    kptr += 64 * DM; vptr += 64;

    for (int kt = 0; kt < KT_PER; ++kt) {
        const int buf = kt & 1;
        __syncthreads();              // staged tile ready (drains vmcnt)
        if (kt + 1 < KT_PER) {
            bf16_t* kd = ksl + (buf ^ 1) * 4096;
            bf16_t* vd = vsl + (buf ^ 1) * 4096;
            async_b128(kd, kptr);     async_b128(kd + 512, kptr + 8);
            async_b128(vd, vptr);     async_b128(vd + 512, vptr + 8);
            kptr += 64 * DM; vptr += 64;
        }

        // K A-frags: A[m=kv=mt*32+c][k=d], chunk = 2s+h32
        bf16x8 Kf[2][4];
#pragma unroll
        for (int mt = 0; mt < 2; ++mt)
#pragma unroll
            for (int s = 0; s < 4; ++s)
                Kf[mt][s] = *(const bf16x8*)&Ks[buf * 4096 + ((2 * s + h32) * 64 + mt * 32 + c) * 8];

        floatx16 sc[2][2] = {};
#pragma unroll
        for (int s = 0; s < 4; ++s)
#pragma unroll
            for (int mt = 0; mt < 2; ++mt)
#pragma unroll
                for (int nt = 0; nt < 2; ++nt)
                    sc[mt][nt] = mfma32(Kf[mt][s], Qf[nt][s], sc[mt][nt]);

        // V A-frags: A[m=d=dt*32+c][k=kv], chunk = 2s+h32
        bf16x8 Vf[2][4];
#pragma unroll
        for (int dt = 0; dt < 2; ++dt)
#pragma unroll
            for (int s = 0; s < 4; ++s)
                Vf[dt][s] = *(const bf16x8*)&Vs[buf * 4096 + ((2 * s + h32) * 64 + dt * 32 + c) * 8];

#pragma unroll
        for (int nt = 0; nt < 2; ++nt) {
            // fixed-max softmax: p = 2^(s_t - 3); per-lane column sums
            bf16x2 pk[2][8];
#pragma unroll
            for (int mt = 0; mt < 2; ++mt)
#pragma unroll
                for (int rr = 0; rr < 8; ++rr) {
                    const float p0 = __builtin_amdgcn_exp2f(sc[mt][nt][2 * rr] - 3.0f);
                    const float p1 = __builtin_amdgcn_exp2f(sc[mt][nt][2 * rr + 1] - 3.0f);
                    la[nt][(2 * rr) & 3] += p0;
                    la[nt][(2 * rr + 1) & 3] += p1;
                    bf16x2 w; w[0] = (bf16_t)p0; w[1] = (bf16_t)p1;
                    pk[mt][rr] = w;
                }
            // P^T C-layout -> B-layout via one cross-half shuffle per dword pair
#pragma unroll
            for (int s = 0; s < 4; ++s) {
                const int a = s >> 1, b4 = (s & 1) * 4;
                const bf16x2 r0 = h32 ? pk[a][b4 + 2] : pk[a][b4 + 0];
                const bf16x2 r1 = h32 ? pk[a][b4 + 3] : pk[a][b4 + 1];
                const bf16x2 s0 = h32 ? pk[a][b4 + 0] : pk[a][b4 + 2];
                const bf16x2 s1 = h32 ? pk[a][b4 + 1] : pk[a][b4 + 3];
                const bf16x2 x0 = i2p(__shfl_xor(p2i(s0), 32));
                const bf16x2 x1 = i2p(__shfl_xor(p2i(s1), 32));
                union { bf16x8 v; bf16x2 d[4]; } P;
                P.d[0] = h32 ? x0 : r0;
                P.d[1] = h32 ? x1 : r1;
                P.d[2] = h32 ? r0 : x0;
                P.d[3] = h32 ? r1 : x1;
                oa[0][nt] = mfma32(Vf[0][s], P.v, oa[0][nt]);
                oa[1][nt] = mfma32(Vf[1][s], P.v, oa[1][nt]);
            }
        }
    }

    // l partials: own half + partner half, store once per column
#pragma unroll
    for (int nt = 0; nt < 2; ++nt) {
        float t = la[nt][0] + la[nt][1] + la[nt][2] + la[nt][3];
        t += i2f(__shfl_xor(f2i(t), 32));
        if (h32 == 0)
            Lpart[(size_t)(sp * NH + head) * S_LEN + qbase + nt * 32 + c] = t;
    }

    // O^T -> q-major fp16 partials via per-wave LDS transpose (aliased on smem)
    __syncthreads();  // all waves done reading Ks/Vs
    f16_t* ot = (f16_t*)smem + wave * (32 * 72);  // 4 waves x 32 q x 72 halfs
#pragma unroll
    for (int nt = 0; nt < 2; ++nt) {
#pragma unroll
        for (int dt = 0; dt < 2; ++dt)
#pragma unroll
            for (int rr = 0; rr < 8; ++rr) {
                const int d0 = dt * 32 + ((2 * rr) & 3) + 8 * (rr >> 1) + 4 * h32;
                f16x2 w;
                w[0] = (f16_t)oa[dt][nt][2 * rr];
                w[1] = (f16_t)oa[dt][nt][2 * rr + 1];
                *(f16x2*)&ot[c * 72 + d0] = w;
            }
        __syncthreads();  // cross-lane LDS visibility (uniform control flow)
        const int r = lane & 31;
#pragma unroll
        for (int j = 0; j < 4; ++j) {
            const f16x8 v = *(const f16x8*)&ot[r * 72 + h32 * 32 + j * 8];
            *(f16x8*)(Opart + ((size_t)sp * S_LEN + qbase + nt * 32 + r) * DM +
                      head * DKH + h32 * 32 + j * 8) = v;
        }
    }
}

// ---------------- reduce partials -> bf16 AO ----------------
__global__ __launch_bounds__(256) void reduce_kernel(
    const f16_t* __restrict__ Op, const float* __restrict__ Lp,
    bf16_t* __restrict__ AO) {
    const size_t f = ((size_t)blockIdx.x * 256 + threadIdx.x) * 8;
    const int q = (int)(f >> 10);
    const int h = (int)((f & 1023) >> 6);
    float l = 0.f;
#pragma unroll
    for (int sp = 0; sp < NSPLIT; ++sp)
        l += Lp[(size_t)(sp * NH + h) * S_LEN + q];
    const float inv = 1.0f / l;
    float s[8] = {};
#pragma unroll
    for (int sp = 0; sp < NSPLIT; ++sp) {
        const f16x8 v = *(const f16x8*)(Op + (size_t)sp * (S_LEN * DM) + f);
#pragma unroll
        for (int j = 0; j < 8; ++j) s[j] += (float)v[j];
    }
    bf16x8 o;
#pragma unroll
    for (int j = 0; j < 8; ++j) o[j] = (bf16_t)(s[j] * inv);
    *(bf16x8*)(AO + f) = o;
}

extern "C" void kernel_launch(void* const* d_in, const int* in_sizes, int n_in,
                              void* d_out, int out_size, void* d_ws, size_t ws_size,
                              hipStream_t stream) {
    const float* q  = (const float*)d_in[0];
    const float* k  = (const float*)d_in[1];
    const float* v  = (const float*)d_in[2];
    const float* Wq = (const float*)d_in[3];
    const float* bq = (const float*)d_in[4];
    const float* Wk = (const float*)d_in[5];
    const float* bk = (const float*)d_in[6];
    const float* Wv = (const float*)d_in[7];
    const float* bv = (const float*)d_in[8];
    const float* Wo = (const float*)d_in[9];
    const float* bo = (const float*)d_in[10];
    float* out = (float*)d_out;

    // Workspace layout (bf16 elements). The 32 MB fp16 Opart overlay covers
    // EXACTLY [qx, kx, vx, Vp] = first 16777216 elems, all dead before flash.
    // Weights wq..wo CONTIGUOUS above the overlay. Total 76.5 MB.
    bf16_t* ws = (bf16_t*)d_ws;
    bf16_t* qx = ws;                          // [0        , 4194304)
    bf16_t* kx = qx + 4194304;                // [4194304  , 8388608)
    bf16_t* vx = kx + 4194304;                // [8388608  , 12582912)
    bf16_t* Vp = vx + 4194304;                // [12582912 , 16777216) dead after transpose
    f16_t*  Opart = (f16_t*)ws;               // overlay [0, 16777216) = 32 MB
    bf16_t* wq = Vp + 4194304;                // contiguous weight block
    bf16_t* wk = wq + 1048576;
    bf16_t* wv = wk + 1048576;
    bf16_t* wo = wv + 1048576;
    bf16_t* Qp = wo + 1048576;
    bf16_t* Kp = Qp + 4194304;
    bf16_t* Vt = Kp + 4194304;
    bf16_t* AO = Vt + 4194304;
    float*  Lpart = (float*)(AO + 4194304);   // 262144 floats

    convert_all_kernel<<<dim3(16384), 256, 0, stream>>>(q, k, v, Wq, Wk, Wv, Wo,
                                                        qx, wq);
    gemm_qkv_kernel<<<dim3(8, 32, 3), 256, 0, stream>>>(qx, kx, vx, wq, wk, wv,
                                                        bq, bk, bv, Qp, Kp, Vp);
    transpose_kernel<<<dim3(16, 64), 256, 0, stream>>>(Vp, Vt);
    flash_kernel<<<dim3(16, 16, NSPLIT), 256, 0, stream>>>(Qp, Kp, Vt, Opart, Lpart);
    reduce_kernel<<<dim3(2048), 256, 0, stream>>>(Opart, Lpart, AO);
    gemm_out_kernel<<<dim3(16, 32), 256, 0, stream>>>(AO, wo, bo, out);
    (void)in_sizes; (void)n_in; (void)out_size; (void)ws_size;
}

// Round 7
// 281.938 us; speedup vs baseline: 2.5527x; 2.5527x over previous
//
#include <hip/hip_runtime.h>
#include <cstdint>
#include <cstddef>

typedef __bf16 bf16_t;
typedef _Float16 f16_t;
typedef __attribute__((ext_vector_type(8))) __bf16 bf16x8;
typedef __attribute__((ext_vector_type(4))) __bf16 bf16x4;
typedef __attribute__((ext_vector_type(2))) __bf16 bf16x2;
typedef __attribute__((ext_vector_type(8))) _Float16 f16x8;
typedef __attribute__((ext_vector_type(2))) _Float16 f16x2;
typedef __attribute__((ext_vector_type(4))) float floatx4;
typedef __attribute__((ext_vector_type(16))) float floatx16;

#define S_LEN 4096
#define DM 1024
#define NH 16
#define DKH 64
#define NSPLIT 4
#define KT_PER (S_LEN / 64 / NSPLIT)   // 16 kv-tiles per split

// scale * log2(e): folded into Q in the projection GEMM epilogue
#define QSCALE 0.1803368801111601f

__device__ __forceinline__ void async_b128(void* lds, const void* g) {
    __builtin_amdgcn_global_load_lds(
        (__attribute__((address_space(1))) void*)(uintptr_t)g,
        (__attribute__((address_space(3))) void*)lds,
        16, 0, 0);
}

// Full counter drain (vmcnt 0, expcnt 0, lgkmcnt 0). The global_load_lds ->
// __syncthreads -> ds_read handoff is only safe if vmcnt is drained before
// s_barrier; the compiler USUALLY emits that drain but it is not guaranteed
// (R6 post-timing nondeterminism). Make it a source-level invariant.
__device__ __forceinline__ void fence_all() { __builtin_amdgcn_s_waitcnt(0); }

__device__ __forceinline__ floatx4 mfma16(bf16x8 a, bf16x8 b, floatx4 c) {
    return __builtin_amdgcn_mfma_f32_16x16x32_bf16(a, b, c, 0, 0, 0);
}
__device__ __forceinline__ floatx16 mfma32(bf16x8 a, bf16x8 b, floatx16 c) {
    return __builtin_amdgcn_mfma_f32_32x32x16_bf16(a, b, c, 0, 0, 0);
}
__device__ __forceinline__ int f2i(float x) { return __builtin_bit_cast(int, x); }
__device__ __forceinline__ float i2f(int x) { return __builtin_bit_cast(float, x); }
__device__ __forceinline__ int p2i(bf16x2 x) { return __builtin_bit_cast(int, x); }
__device__ __forceinline__ bf16x2 i2p(int x) { return __builtin_bit_cast(bf16x2, x); }

// ------- fused fp32 -> bf16 conversion: inputs (12.58M) + weights (4.19M) ----
__global__ __launch_bounds__(256) void convert_all_kernel(
    const float* __restrict__ q, const float* __restrict__ k,
    const float* __restrict__ v, const float* __restrict__ wqf,
    const float* __restrict__ wkf, const float* __restrict__ wvf,
    const float* __restrict__ wof, bf16_t* __restrict__ dst_in,
    bf16_t* __restrict__ dst_w) {
    const size_t i = ((size_t)blockIdx.x * 256 + threadIdx.x) * 4;
    const float* s;
    bf16_t* d;
    size_t off;
    if (i < 12582912) {                  // 3 x 4194304 input elems
        const int r = (int)(i >> 22);
        s = (r == 0) ? q : (r == 1) ? k : v;
        off = i & 4194303;
        d = dst_in + (size_t)r * 4194304 + off;
    } else {                             // 4 x 1048576 weight elems
        const size_t j = i - 12582912;
        const int r = (int)(j >> 20);
        s = (r == 0) ? wqf : (r == 1) ? wkf : (r == 2) ? wvf : wof;
        off = j & 1048575;
        d = dst_w + (size_t)r * 1048576 + off;
    }
    const floatx4 val = *(const floatx4*)(s + off);
    bf16x4 o;
    o[0] = (bf16_t)val[0]; o[1] = (bf16_t)val[1];
    o[2] = (bf16_t)val[2]; o[3] = (bf16_t)val[3];
    *(bf16x4*)d = o;
}

// ------- GEMM: C[M,N] = (A[M,K] @ B[N,K]^T + bias[N]) * oscale, 128xBN tile -
template <int BN, typename OutT>
__device__ __forceinline__ void gemm_bt_body(const bf16_t* __restrict__ A,
                                             const bf16_t* __restrict__ B,
                                             const float* __restrict__ bias,
                                             OutT* __restrict__ C, float oscale) {
    constexpr int K = 1024, N = 1024;
    constexpr int NT = BN / 32;          // n-tiles of 16 per wave
    __shared__ bf16_t As[128 * 32];
    __shared__ bf16_t Bs[BN * 32];
    const int tid = threadIdx.x;
    const int wid = tid >> 6, lane = tid & 63;
    const int quad = lane >> 4, l16 = lane & 15;
    const int m0 = blockIdx.y * 128, n0 = blockIdx.x * BN;
    const int wm = (wid & 1) * 64, wn = (wid >> 1) * (BN / 2);

    floatx4 acc[4][NT] = {};

    for (int k0 = 0; k0 < K; k0 += 32) {
        __syncthreads();
#pragma unroll
        for (int i = 0; i < 2; ++i) {
            const int c = (i << 8) + tid;
            const int row = c >> 2;
            const int ko = (c & 3) << 3;
            const int lb = ((i << 8) + (wid << 6)) << 3;
            async_b128(&As[lb], A + (size_t)(m0 + row) * K + k0 + ko);
        }
#pragma unroll
        for (int i = 0; i < BN / 64; ++i) {
            const int c = (i << 8) + tid;
            const int row = c >> 2;
            const int ko = (c & 3) << 3;
            const int lb = ((i << 8) + (wid << 6)) << 3;
            async_b128(&Bs[lb], B + (size_t)(n0 + row) * K + k0 + ko);
        }
        fence_all();
        __syncthreads();

        bf16x8 af[4], bfr[NT];
#pragma unroll
        for (int t = 0; t < 4; ++t)
            af[t] = *(const bf16x8*)&As[(wm + t * 16 + l16) * 32 + quad * 8];
#pragma unroll
        for (int t = 0; t < NT; ++t)
            bfr[t] = *(const bf16x8*)&Bs[(wn + t * 16 + l16) * 32 + quad * 8];
#pragma unroll
        for (int mt = 0; mt < 4; ++mt)
#pragma unroll
            for (int nt = 0; nt < NT; ++nt)
                acc[mt][nt] = mfma16(af[mt], bfr[nt], acc[mt][nt]);
    }

#pragma unroll
    for (int mt = 0; mt < 4; ++mt)
#pragma unroll
        for (int nt = 0; nt < NT; ++nt) {
            const int col = n0 + wn + nt * 16 + l16;
            const float bv = bias[col];
#pragma unroll
            for (int r = 0; r < 4; ++r) {
                const int row = m0 + wm + mt * 16 + quad * 4 + r;
                C[(size_t)row * N + col] = (OutT)((acc[mt][nt][r] + bv) * oscale);
            }
        }
}

__global__ __launch_bounds__(256) void gemm_qkv_kernel(
    const bf16_t* __restrict__ qx, const bf16_t* __restrict__ kx,
    const bf16_t* __restrict__ vx, const bf16_t* __restrict__ wq,
    const bf16_t* __restrict__ wk, const bf16_t* __restrict__ wv,
    const float* __restrict__ bq, const float* __restrict__ bk,
    const float* __restrict__ bv, bf16_t* __restrict__ Qp,
    bf16_t* __restrict__ Kp, bf16_t* __restrict__ Vp) {
    const int z = blockIdx.z;
    const bf16_t* A = (z == 0) ? qx : (z == 1) ? kx : vx;
    const bf16_t* B = (z == 0) ? wq : (z == 1) ? wk : wv;
    const float* bias = (z == 0) ? bq : (z == 1) ? bk : bv;
    bf16_t* C = (z == 0) ? Qp : (z == 1) ? Kp : Vp;
    gemm_bt_body<128, bf16_t>(A, B, bias, C, (z == 0) ? QSCALE : 1.0f);
}

__global__ __launch_bounds__(256) void gemm_out_kernel(
    const bf16_t* __restrict__ AO, const bf16_t* __restrict__ wo,
    const float* __restrict__ bo, float* __restrict__ out) {
    gemm_bt_body<64, float>(AO, wo, bo, out, 1.0f);
}

// ---------------- transpose Vp[4096,1024] -> Vt[1024,4096] ----------------
__global__ __launch_bounds__(256) void transpose_kernel(
    const bf16_t* __restrict__ in, bf16_t* __restrict__ out) {
    __shared__ bf16_t tile[64][65];
    const int tx = threadIdx.x & 63;
    const int ty = threadIdx.x >> 6;
    const int c0 = blockIdx.x * 64;
    const int r0 = blockIdx.y * 64;
#pragma unroll
    for (int i = 0; i < 16; ++i) {
        const int r = ty + i * 4;
        tile[r][tx] = in[(size_t)(r0 + r) * DM + c0 + tx];
    }
    __syncthreads();
#pragma unroll
    for (int i = 0; i < 16; ++i) {
        const int c = ty + i * 4;
        out[(size_t)(c0 + c) * S_LEN + r0 + tx] = tile[tx][c];
    }
}

// ---------------- flash attention, S^T formulation, kv-split ----------------
// Fixed-max softmax p=2^(s-3) is associative over kv. 4 waves/block share one
// 32KB double-buffered K/V tile; each wave owns 64 q columns.
// grid (16 q-blocks of 256, 16 heads, 4 splits), 256 thr.
// __launch_bounds__(256, 2): VGPR cap 256/wave — (256,4)'s 128-cap caused
// massive scratch spills (R5). Explicit fence_all() before every barrier:
// the async-LDS handoff must not depend on compiler drain choices (R6).
__global__ __launch_bounds__(256, 2) void flash_kernel(
    const bf16_t* __restrict__ Q, const bf16_t* __restrict__ K,
    const bf16_t* __restrict__ Vt, f16_t* __restrict__ Opart,
    float* __restrict__ Lpart) {
    // 32 KB: Ks[2][4096] at 0, Vs[2][4096] at 8192; epilogue scratch aliased
    __shared__ bf16_t smem[16384];
    bf16_t* Ks = smem;
    bf16_t* Vs = smem + 8192;

    const int tid = threadIdx.x;
    const int wave = tid >> 6, lane = tid & 63;
    const int h32 = lane >> 5, c = lane & 31;
    const int head = blockIdx.y;
    const int sp = blockIdx.z;
    const int qbase = blockIdx.x * 256 + wave * 64;
    const int kv0 = sp * (S_LEN / NSPLIT);

    // Q B-frags in registers (pre-scaled by QSCALE): B[n=q=c][k=d]
    bf16x8 Qf[2][4];
#pragma unroll
    for (int nt = 0; nt < 2; ++nt)
#pragma unroll
        for (int s = 0; s < 4; ++s)
            Qf[nt][s] = *(const bf16x8*)(Q + (size_t)(qbase + nt * 32 + c) * DM +
                                         head * DKH + s * 16 + h32 * 8);

    floatx16 oa[2][2] = {};
    floatx4 la[2] = {};

    // staging: wave w stages chunks {2w, 2w+1} of K (d-split) and V (kv-split)
    const bf16_t* kptr = K + (size_t)(kv0 + lane) * DM + head * DKH + wave * 16;
    const bf16_t* vptr = Vt + (size_t)(head * DKH + lane) * S_LEN + kv0 + wave * 16;
    bf16_t* ksl = Ks + wave * 1024;
    bf16_t* vsl = Vs + wave * 1024;

    async_b128(ksl, kptr);       async_b128(ksl + 512, kptr + 8);
    async_b128(vsl, vptr);       async_b128(vsl + 512, vptr + 8);
    kptr += 64 * DM; vptr += 64;

    for (int kt = 0; kt < KT_PER; ++kt) {
        const int buf = kt & 1;
        fence_all();                  // drain OUR async loads before barrier
        __syncthreads();              // staged tile ready for all waves
        if (kt + 1 < KT_PER) {
            bf16_t* kd = ksl + (buf ^ 1) * 4096;
            bf16_t* vd = vsl + (buf ^ 1) * 4096;
            async_b128(kd, kptr);     async_b128(kd + 512, kptr + 8);
            async_b128(vd, vptr);     async_b128(vd + 512, vptr + 8);
            kptr += 64 * DM; vptr += 64;
        }

        // K A-frags: A[m=kv=mt*32+c][k=d], chunk = 2s+h32
        bf16x8 Kf[2][4];
#pragma unroll
        for (int mt = 0; mt < 2; ++mt)
#pragma unroll
            for (int s = 0; s < 4; ++s)
                Kf[mt][s] = *(const bf16x8*)&Ks[buf * 4096 + ((2 * s + h32) * 64 + mt * 32 + c) * 8];

        floatx16 sc[2][2] = {};
#pragma unroll
        for (int s = 0; s < 4; ++s)
#pragma unroll
            for (int mt = 0; mt < 2; ++mt)
#pragma unroll
                for (int nt = 0; nt < 2; ++nt)
                    sc[mt][nt] = mfma32(Kf[mt][s], Qf[nt][s], sc[mt][nt]);

        // V A-frags: A[m=d=dt*32+c][k=kv], chunk = 2s+h32
        bf16x8 Vf[2][4];
#pragma unroll
        for (int dt = 0; dt < 2; ++dt)
#pragma unroll
            for (int s = 0; s < 4; ++s)
                Vf[dt][s] = *(const bf16x8*)&Vs[buf * 4096 + ((2 * s + h32) * 64 + dt * 32 + c) * 8];

#pragma unroll
        for (int nt = 0; nt < 2; ++nt) {
            // fixed-max softmax: p = 2^(s_t - 3); per-lane column sums
            bf16x2 pk[2][8];
#pragma unroll
            for (int mt = 0; mt < 2; ++mt)
#pragma unroll
                for (int rr = 0; rr < 8; ++rr) {
                    const float p0 = __builtin_amdgcn_exp2f(sc[mt][nt][2 * rr] - 3.0f);
                    const float p1 = __builtin_amdgcn_exp2f(sc[mt][nt][2 * rr + 1] - 3.0f);
                    la[nt][(2 * rr) & 3] += p0;
                    la[nt][(2 * rr + 1) & 3] += p1;
                    bf16x2 w; w[0] = (bf16_t)p0; w[1] = (bf16_t)p1;
                    pk[mt][rr] = w;
                }
            // P^T C-layout -> B-layout via one cross-half shuffle per dword pair
#pragma unroll
            for (int s = 0; s < 4; ++s) {
                const int a = s >> 1, b4 = (s & 1) * 4;
                const bf16x2 r0 = h32 ? pk[a][b4 + 2] : pk[a][b4 + 0];
                const bf16x2 r1 = h32 ? pk[a][b4 + 3] : pk[a][b4 + 1];
                const bf16x2 s0 = h32 ? pk[a][b4 + 0] : pk[a][b4 + 2];
                const bf16x2 s1 = h32 ? pk[a][b4 + 1] : pk[a][b4 + 3];
                const bf16x2 x0 = i2p(__shfl_xor(p2i(s0), 32));
                const bf16x2 x1 = i2p(__shfl_xor(p2i(s1), 32));
                union { bf16x8 v; bf16x2 d[4]; } P;
                P.d[0] = h32 ? x0 : r0;
                P.d[1] = h32 ? x1 : r1;
                P.d[2] = h32 ? r0 : x0;
                P.d[3] = h32 ? r1 : x1;
                oa[0][nt] = mfma32(Vf[0][s], P.v, oa[0][nt]);
                oa[1][nt] = mfma32(Vf[1][s], P.v, oa[1][nt]);
            }
        }
    }

    // l partials: own half + partner half, store once per column
#pragma unroll
    for (int nt = 0; nt < 2; ++nt) {
        float t = la[nt][0] + la[nt][1] + la[nt][2] + la[nt][3];
        t += i2f(__shfl_xor(f2i(t), 32));
        if (h32 == 0)
            Lpart[(size_t)(sp * NH + head) * S_LEN + qbase + nt * 32 + c] = t;
    }

    // O^T -> q-major fp16 partials via per-wave LDS transpose (aliased on smem)
    fence_all();
    __syncthreads();  // all waves done reading Ks/Vs
    f16_t* ot = (f16_t*)smem + wave * (32 * 72);  // 4 waves x 32 q x 72 halfs
#pragma unroll
    for (int nt = 0; nt < 2; ++nt) {
#pragma unroll
        for (int dt = 0; dt < 2; ++dt)
#pragma unroll
            for (int rr = 0; rr < 8; ++rr) {
                const int d0 = dt * 32 + ((2 * rr) & 3) + 8 * (rr >> 1) + 4 * h32;
                f16x2 w;
                w[0] = (f16_t)oa[dt][nt][2 * rr];
                w[1] = (f16_t)oa[dt][nt][2 * rr + 1];
                *(f16x2*)&ot[c * 72 + d0] = w;
            }
        fence_all();
        __syncthreads();  // cross-lane LDS visibility (uniform control flow)
        const int r = lane & 31;
#pragma unroll
        for (int j = 0; j < 4; ++j) {
            const f16x8 v = *(const f16x8*)&ot[r * 72 + h32 * 32 + j * 8];
            *(f16x8*)(Opart + ((size_t)sp * S_LEN + qbase + nt * 32 + r) * DM +
                      head * DKH + h32 * 32 + j * 8) = v;
        }
        fence_all();
        __syncthreads();  // reads done before next nt overwrites ot
    }
}

// ---------------- reduce partials -> bf16 AO ----------------
__global__ __launch_bounds__(256) void reduce_kernel(
    const f16_t* __restrict__ Op, const float* __restrict__ Lp,
    bf16_t* __restrict__ AO) {
    const size_t f = ((size_t)blockIdx.x * 256 + threadIdx.x) * 8;
    const int q = (int)(f >> 10);
    const int h = (int)((f & 1023) >> 6);
    float l = 0.f;
#pragma unroll
    for (int sp = 0; sp < NSPLIT; ++sp)
        l += Lp[(size_t)(sp * NH + h) * S_LEN + q];
    const float inv = 1.0f / l;
    float s[8] = {};
#pragma unroll
    for (int sp = 0; sp < NSPLIT; ++sp) {
        const f16x8 v = *(const f16x8*)(Op + (size_t)sp * (S_LEN * DM) + f);
#pragma unroll
        for (int j = 0; j < 8; ++j) s[j] += (float)v[j];
    }
    bf16x8 o;
#pragma unroll
    for (int j = 0; j < 8; ++j) o[j] = (bf16_t)(s[j] * inv);
    *(bf16x8*)(AO + f) = o;
}

extern "C" void kernel_launch(void* const* d_in, const int* in_sizes, int n_in,
                              void* d_out, int out_size, void* d_ws, size_t ws_size,
                              hipStream_t stream) {
    const float* q  = (const float*)d_in[0];
    const float* k  = (const float*)d_in[1];
    const float* v  = (const float*)d_in[2];
    const float* Wq = (const float*)d_in[3];
    const float* bq = (const float*)d_in[4];
    const float* Wk = (const float*)d_in[5];
    const float* bk = (const float*)d_in[6];
    const float* Wv = (const float*)d_in[7];
    const float* bv = (const float*)d_in[8];
    const float* Wo = (const float*)d_in[9];
    const float* bo = (const float*)d_in[10];
    float* out = (float*)d_out;

    // Workspace layout (bf16 elements). The 32 MB fp16 Opart overlay covers
    // EXACTLY [qx, kx, vx, Vp] = first 16777216 elems, all dead before flash.
    // Weights wq..wo CONTIGUOUS above the overlay. Total 76.5 MB.
    bf16_t* ws = (bf16_t*)d_ws;
    bf16_t* qx = ws;                          // [0        , 4194304)
    bf16_t* kx = qx + 4194304;                // [4194304  , 8388608)
    bf16_t* vx = kx + 4194304;                // [8388608  , 12582912)
    bf16_t* Vp = vx + 4194304;                // [12582912 , 16777216) dead after transpose
    f16_t*  Opart = (f16_t*)ws;               // overlay [0, 16777216) = 32 MB
    bf16_t* wq = Vp + 4194304;                // contiguous weight block
    bf16_t* wk = wq + 1048576;
    bf16_t* wv = wk + 1048576;
    bf16_t* wo = wv + 1048576;
    bf16_t* Qp = wo + 1048576;
    bf16_t* Kp = Qp + 4194304;
    bf16_t* Vt = Kp + 4194304;
    bf16_t* AO = Vt + 4194304;
    float*  Lpart = (float*)(AO + 4194304);   // 262144 floats

    convert_all_kernel<<<dim3(16384), 256, 0, stream>>>(q, k, v, Wq, Wk, Wv, Wo,
                                                        qx, wq);
    gemm_qkv_kernel<<<dim3(8, 32, 3), 256, 0, stream>>>(qx, kx, vx, wq, wk, wv,
                                                        bq, bk, bv, Qp, Kp, Vp);
    transpose_kernel<<<dim3(16, 64), 256, 0, stream>>>(Vp, Vt);
    flash_kernel<<<dim3(16, 16, NSPLIT), 256, 0, stream>>>(Qp, Kp, Vt, Opart, Lpart);
    reduce_kernel<<<dim3(2048), 256, 0, stream>>>(Opart, Lpart, AO);
    gemm_out_kernel<<<dim3(16, 32), 256, 0, stream>>>(AO, wo, bo, out);
    (void)in_sizes; (void)n_in; (void)out_size; (void)ws_size;
}